// Round 11
// baseline (344.093 us; speedup 1.0000x reference)
//
#include <hip/hip_runtime.h>

// Problem: B=4, N=512, D=256, H=256, M = B*N = 2048
// out[b,i,j] = 0.5*(E + E^T),  E[b,i,j] = sum_h v[h]*tanh(Q[b,i,h]+K[b,j,h])
// tanh(q+k) = 1 - 2/(1+e^{2q}e^{2k}); u=exp2(C2*q), w=exp2(C2*k), C2=2*log2(e)
// P_ij = sum_h v_h/(1+u_ih w_jh);  out_ij = Sv - P_ij - P_ji  (symmetric!)
// 8-way rcp batching (1 rcp / 8 terms) via common-denominator tree.
// Overflow: u pre-scaled 2^-8 (clamp 4), w clamp 1024; leaf A=fma(u',w,2^-8);
//   M = prod8 <= 4096^8 ~ 8e28 safe; fold 2^-8 into final store.
// Round 11: triangular tile-pair blocks compute BOTH directions and write
// out directly (atomicAdd onto Sv-initialized out). sym kernel + Ep deleted.

typedef float f4 __attribute__((ext_vector_type(4)));
typedef float f32x4 __attribute__((ext_vector_type(4)));
typedef __bf16 bf16x8 __attribute__((ext_vector_type(8)));

#define C2F 2.8853900817779268f
#define S8  0.00390625f   // 2^-8

__constant__ int TI36[36] = {0,0,0,0,0,0,0,0, 1,1,1,1,1,1,1, 2,2,2,2,2,2,
                             3,3,3,3,3, 4,4,4,4, 5,5,5, 6,6, 7};
__constant__ int TJ36[36] = {0,1,2,3,4,5,6,7, 1,2,3,4,5,6,7, 2,3,4,5,6,7,
                             3,4,5,6,7, 4,5,6,7, 5,6,7, 6,7, 7};

__device__ inline unsigned short f2bf(float f) {
    unsigned u = __float_as_uint(f);
    unsigned r = (u + 0x7fffu + ((u >> 16) & 1u)) >> 16;
    return (unsigned short)r;
}
__device__ inline float bf2f(unsigned short h) {
    return __uint_as_float(((unsigned)h) << 16);
}

__device__ inline void split4(const f4 a, unsigned short* hp, unsigned short* lp) {
    unsigned short h[4], l[4];
#pragma unroll
    for (int t = 0; t < 4; ++t) {
        h[t] = f2bf(a[t]);
        l[t] = f2bf(a[t] - bf2f(h[t]));
    }
    uint2 hv, lv;
    hv.x = (unsigned)h[0] | ((unsigned)h[1] << 16);
    hv.y = (unsigned)h[2] | ((unsigned)h[3] << 16);
    lv.x = (unsigned)l[0] | ((unsigned)l[1] << 16);
    lv.y = (unsigned)l[2] | ((unsigned)l[3] << 16);
    *(uint2*)hp = hv;
    *(uint2*)lp = lv;
}

// ---------------------------------------------------------------------------
// gemm_fullk: C[m,n] = act(sum_k A[m,k]*Wsel[n,k] + bias[n]), K=256 resident.
// ACT==2: col<256 -> min(exp2(C2*x-8),4); col>=256 -> min(exp2(C2*x),1024)
// ---------------------------------------------------------------------------
template <int ACT>
__global__ __launch_bounds__(256) void gemm_fullk(
    const float* __restrict__ A, const float* __restrict__ Wa,
    const float* __restrict__ Wb, const float* __restrict__ ba,
    const float* __restrict__ bb2, float* __restrict__ C, int Nn) {
    __shared__ unsigned short sAhi[64][264];
    __shared__ unsigned short sAlo[64][264];
    __shared__ unsigned short sBhi[64][264];
    __shared__ unsigned short sBlo[64][264];

    const int tid = threadIdx.x;
    const int m0 = blockIdx.x << 6;
    const int n0 = blockIdx.y << 6;

    const float* Atile = A + (size_t)m0 * 256;
    const float* Wtile = (n0 < 256) ? (Wa + (size_t)n0 * 256)
                                    : (Wb + (size_t)(n0 - 256) * 256);
    const int col4 = (tid & 63) << 2;
    const int rgrp = tid >> 6;
#pragma unroll
    for (int t = 0; t < 16; ++t) {
        const int row = (t << 2) + rgrp;
        f4 av = *(const f4*)&Atile[(size_t)row * 256 + col4];
        f4 wv = *(const f4*)&Wtile[(size_t)row * 256 + col4];
        split4(av, &sAhi[row][col4], &sAlo[row][col4]);
        split4(wv, &sBhi[row][col4], &sBlo[row][col4]);
    }
    __syncthreads();

    const int lane = tid & 63;
    const int wav = tid >> 6;
    const int wm = wav >> 1, wn = wav & 1;
    const int fr = lane & 15;
    const int fks = (lane >> 4) << 3;

    f32x4 acc[2][2];
#pragma unroll
    for (int i = 0; i < 2; ++i)
#pragma unroll
        for (int j = 0; j < 2; ++j) acc[i][j] = (f32x4){0.f, 0.f, 0.f, 0.f};

#pragma unroll
    for (int kt = 0; kt < 256; kt += 32) {
        bf16x8 ah[2], al[2], bh[2], bl[2];
#pragma unroll
        for (int s = 0; s < 2; ++s) {
            ah[s] = *(const bf16x8*)&sAhi[(wm << 5) + (s << 4) + fr][kt + fks];
            al[s] = *(const bf16x8*)&sAlo[(wm << 5) + (s << 4) + fr][kt + fks];
            bh[s] = *(const bf16x8*)&sBhi[(wn << 5) + (s << 4) + fr][kt + fks];
            bl[s] = *(const bf16x8*)&sBlo[(wn << 5) + (s << 4) + fr][kt + fks];
        }
#pragma unroll
        for (int i = 0; i < 2; ++i)
#pragma unroll
            for (int j = 0; j < 2; ++j) {
                acc[i][j] = __builtin_amdgcn_mfma_f32_16x16x32_bf16(ah[i], bh[j], acc[i][j], 0, 0, 0);
                acc[i][j] = __builtin_amdgcn_mfma_f32_16x16x32_bf16(ah[i], bl[j], acc[i][j], 0, 0, 0);
                acc[i][j] = __builtin_amdgcn_mfma_f32_16x16x32_bf16(al[i], bh[j], acc[i][j], 0, 0, 0);
            }
    }

    const int rbase = (lane >> 4) << 2;
#pragma unroll
    for (int i = 0; i < 2; ++i) {
#pragma unroll
        for (int j = 0; j < 2; ++j) {
            const int gcol = n0 + (wn << 5) + (j << 4) + fr;
            const float bias = (ACT == 2 && gcol >= 256) ? bb2[gcol - 256] : ba[gcol];
#pragma unroll
            for (int q = 0; q < 4; ++q) {
                const int grow = m0 + (wm << 5) + (i << 4) + rbase + q;
                float x = acc[i][j][q] + bias;
                if (ACT == 1)
                    x = 1.0f - 2.0f * __builtin_amdgcn_rcpf(
                                          1.0f + __builtin_amdgcn_exp2f(C2F * x));
                if (ACT == 2) {
                    if (gcol < 256)
                        x = fminf(__builtin_amdgcn_exp2f(C2F * x - 8.0f), 4.0f);
                    else
                        x = fminf(__builtin_amdgcn_exp2f(C2F * x), 1024.0f);
                }
                C[(size_t)grow * Nn + gcol] = x;
            }
        }
    }
}

// ---------------------------------------------------------------------------
// gemm_stage1: fused launch.
//  blocks [0,128): h1 = tanh(X @ W1^T + b1)
//  blocks [128,160): Wc = [Wq;Wk] @ W2 (B not transp.), bc = Asel@b2 + bias
//  blocks [160,416): out init to Sv = sum(v)  (4MB fill, replaces sym's Sv)
// ---------------------------------------------------------------------------
__global__ __launch_bounds__(256) void gemm_stage1(
    const float* __restrict__ X, const float* __restrict__ W1,
    const float* __restrict__ b1, const float* __restrict__ Wq,
    const float* __restrict__ Wk, const float* __restrict__ W2,
    const float* __restrict__ b2, const float* __restrict__ bq,
    const float* __restrict__ bk, const float* __restrict__ v,
    float* __restrict__ h1, float* __restrict__ Wc, float* __restrict__ bc,
    float* __restrict__ out) {
    __shared__ unsigned short sAhi[64][264];
    __shared__ unsigned short sAlo[64][264];
    __shared__ unsigned short sBhi[64][264];
    __shared__ unsigned short sBlo[64][264];
    __shared__ float sred[64][4];

    const int tid = threadIdx.x;

    if (blockIdx.x >= 160) {
        // out init: 256 blocks x 4096 floats = 1048576
        float x = v[tid];
#pragma unroll
        for (int o = 32; o > 0; o >>= 1) x += __shfl_xor(x, o, 64);
        if ((tid & 63) == 0) sred[0][tid >> 6] = x;
        __syncthreads();
        const float Sv = sred[0][0] + sred[0][1] + sred[0][2] + sred[0][3];
        const int zb = blockIdx.x - 160;
        f4* dst = (f4*)(out + (size_t)zb * 4096) + tid;
        const f4 s = (f4){Sv, Sv, Sv, Sv};
#pragma unroll
        for (int t = 0; t < 4; ++t) dst[t * 256] = s;
        return;
    }

    const bool is_nt = (blockIdx.x >= 128);
    const int blk = is_nt ? (blockIdx.x - 128) : blockIdx.x;
    const int m0 = (blk >> 2) << 6;
    const int n0 = (blk & 3) << 6;

    const int col4 = (tid & 63) << 2;
    const int rgrp = tid >> 6;

    if (!is_nt) {
        const float* Atile = X + (size_t)m0 * 256;
        const float* Wtile = W1 + (size_t)n0 * 256;
#pragma unroll
        for (int t = 0; t < 16; ++t) {
            const int row = (t << 2) + rgrp;
            f4 av = *(const f4*)&Atile[(size_t)row * 256 + col4];
            f4 wv = *(const f4*)&Wtile[(size_t)row * 256 + col4];
            split4(av, &sAhi[row][col4], &sAlo[row][col4]);
            split4(wv, &sBhi[row][col4], &sBlo[row][col4]);
        }
    } else {
        const float* Atile = (m0 < 256) ? (Wq + (size_t)m0 * 256)
                                        : (Wk + (size_t)(m0 - 256) * 256);
#pragma unroll
        for (int t = 0; t < 16; ++t) {
            const int row = (t << 2) + rgrp;
            f4 av = *(const f4*)&Atile[(size_t)row * 256 + col4];
            split4(av, &sAhi[row][col4], &sAlo[row][col4]);
        }
        const int c4 = (tid & 15) << 2;
        const int kg = tid >> 4;
#pragma unroll
        for (int t = 0; t < 16; ++t) {
            const int k = (t << 4) + kg;
            f4 wv = *(const f4*)&W2[(size_t)k * 256 + n0 + c4];
#pragma unroll
            for (int q = 0; q < 4; ++q) {
                unsigned short hi = f2bf(wv[q]);
                sBhi[c4 + q][k] = hi;
                sBlo[c4 + q][k] = f2bf(wv[q] - bf2f(hi));
            }
        }
    }
    __syncthreads();

    const int lane = tid & 63;
    const int wav = tid >> 6;
    const int wm = wav >> 1, wn = wav & 1;
    const int fr = lane & 15;
    const int fks = (lane >> 4) << 3;

    f32x4 acc[2][2];
#pragma unroll
    for (int i = 0; i < 2; ++i)
#pragma unroll
        for (int j = 0; j < 2; ++j) acc[i][j] = (f32x4){0.f, 0.f, 0.f, 0.f};

#pragma unroll
    for (int kt = 0; kt < 256; kt += 32) {
        bf16x8 ah[2], al[2], bh[2], bl[2];
#pragma unroll
        for (int s = 0; s < 2; ++s) {
            ah[s] = *(const bf16x8*)&sAhi[(wm << 5) + (s << 4) + fr][kt + fks];
            al[s] = *(const bf16x8*)&sAlo[(wm << 5) + (s << 4) + fr][kt + fks];
            bh[s] = *(const bf16x8*)&sBhi[(wn << 5) + (s << 4) + fr][kt + fks];
            bl[s] = *(const bf16x8*)&sBlo[(wn << 5) + (s << 4) + fr][kt + fks];
        }
#pragma unroll
        for (int i = 0; i < 2; ++i)
#pragma unroll
            for (int j = 0; j < 2; ++j) {
                acc[i][j] = __builtin_amdgcn_mfma_f32_16x16x32_bf16(ah[i], bh[j], acc[i][j], 0, 0, 0);
                acc[i][j] = __builtin_amdgcn_mfma_f32_16x16x32_bf16(ah[i], bl[j], acc[i][j], 0, 0, 0);
                acc[i][j] = __builtin_amdgcn_mfma_f32_16x16x32_bf16(al[i], bh[j], acc[i][j], 0, 0, 0);
            }
    }

    const int rbase = (lane >> 4) << 2;
    if (!is_nt) {
#pragma unroll
        for (int i = 0; i < 2; ++i)
#pragma unroll
            for (int j = 0; j < 2; ++j) {
                const int gcol = n0 + (wn << 5) + (j << 4) + fr;
                const float bias = b1[gcol];
#pragma unroll
                for (int q = 0; q < 4; ++q) {
                    const int grow = m0 + (wm << 5) + (i << 4) + rbase + q;
                    float x = acc[i][j][q] + bias;
                    x = 1.0f - 2.0f * __builtin_amdgcn_rcpf(
                                          1.0f + __builtin_amdgcn_exp2f(C2F * x));
                    h1[(size_t)grow * 256 + gcol] = x;
                }
            }
    } else {
#pragma unroll
        for (int i = 0; i < 2; ++i)
#pragma unroll
            for (int j = 0; j < 2; ++j) {
                const int gcol = n0 + (wn << 5) + (j << 4) + fr;
#pragma unroll
                for (int q = 0; q < 4; ++q) {
                    const int grow = m0 + (wm << 5) + (i << 4) + rbase + q;
                    Wc[(size_t)grow * 256 + gcol] = acc[i][j][q];
                }
            }
        if ((blk & 3) == 0) {
            const int rr = tid >> 2;
            const int part = (tid & 3) << 6;
            const int grow = m0 + rr;
            const float* Ar = (grow < 256) ? &Wq[(size_t)grow * 256]
                                           : &Wk[(size_t)(grow - 256) * 256];
            float s = 0.f;
#pragma unroll
            for (int e = 0; e < 64; e += 4) {
                f4 a = *(const f4*)&Ar[part + e];
                f4 bv = *(const f4*)&b2[part + e];
                s += a[0] * bv[0] + a[1] * bv[1] + a[2] * bv[2] + a[3] * bv[3];
            }
            sred[rr][tid & 3] = s;
            __syncthreads();
            if (tid < 64) {
                float bias = sred[tid][0] + sred[tid][1] + sred[tid][2] + sred[tid][3];
                const int g2 = m0 + tid;
                bias += (g2 < 256) ? bq[g2] : bk[g2 - 256];
                bc[g2] = bias;
            }
        }
    }
}

// 8-way tree for one (row-val u[8], col-val w[8], v[8]) group
#define TREE8(u0, u1, wv0, wv1, vv0, vv1, ACCV)                              \
    {                                                                        \
        const float A0 = fmaf(u0.x, wv0.x, S8);                              \
        const float A1 = fmaf(u0.y, wv0.y, S8);                              \
        const float A2 = fmaf(u0.z, wv0.z, S8);                              \
        const float A3 = fmaf(u0.w, wv0.w, S8);                              \
        const float A4 = fmaf(u1.x, wv1.x, S8);                              \
        const float A5 = fmaf(u1.y, wv1.y, S8);                              \
        const float A6 = fmaf(u1.z, wv1.z, S8);                              \
        const float A7 = fmaf(u1.w, wv1.w, S8);                              \
        const float m01 = A0 * A1, m23 = A2 * A3;                            \
        const float m45 = A4 * A5, m67 = A6 * A7;                            \
        const float t01 = fmaf(vv0.x, A1, vv0.y * A0);                       \
        const float t23 = fmaf(vv0.z, A3, vv0.w * A2);                       \
        const float t45 = fmaf(vv1.x, A5, vv1.y * A4);                       \
        const float t67 = fmaf(vv1.z, A7, vv1.w * A6);                       \
        const float m03 = m01 * m23, m47 = m45 * m67;                        \
        const float t03 = fmaf(t01, m23, t23 * m01);                         \
        const float t47 = fmaf(t45, m67, t67 * m45);                         \
        const float M = m03 * m47;                                           \
        const float N = fmaf(t03, m47, t47 * m03);                           \
        ACCV = fmaf(N, __builtin_amdgcn_rcpf(M), ACCV);                      \
    }

// ---------------------------------------------------------------------------
// pairwise_tri: per (b, tile-pair ti<=tj, 32-h chunk) block.
//   Off-diag: acc1 = P[i0+r, j0+c], acc2 = P[j0+c, i0+r] (same thread owns
//   both), val = -(acc1+acc2)*S8; atomicAdd to out[i0+r,j0+c]; mirror tile
//   staged in LDS, coalesced atomicAdd to out[j0+c,i0+r].
//   Diag: acc1 only; transpose via LDS; val = -(T[r][c]+T[c][r])*S8.
// out pre-initialized to Sv.  512 thr; LDS 4x[64][36] + T[64][65] (reused).
// ---------------------------------------------------------------------------
__global__ __launch_bounds__(512, 4) void pairwise_tri(
    const float* __restrict__ uwb, const float* __restrict__ v,
    float* __restrict__ out) {
    __shared__ float LDSBUF[9216];   // 36 KB staging; T[64][65] reuses front
    __shared__ float sV[32];
    float(*sUi)[36] = (float(*)[36])(LDSBUF);
    float(*sWj)[36] = (float(*)[36])(LDSBUF + 2304);
    float(*sUj)[36] = (float(*)[36])(LDSBUF + 4608);
    float(*sWi)[36] = (float(*)[36])(LDSBUF + 6912);
    float(*T)[65] = (float(*)[65])(LDSBUF);

    const int tid = threadIdx.x;
    const int bb = blockIdx.x;            // 1152 = 4b * 36 pairs * 8 chunks
    const int hc = (bb & 7) << 5;
    const int tt = bb >> 3;
    const int b = tt / 36;
    const int tp = tt - b * 36;
    const int ti = TI36[tp], tj = TJ36[tp];
    const int i0 = ti << 6, j0 = tj << 6;
    const bool diag = (ti == tj);

    const float* Ub = uwb + ((size_t)(b << 9)) * 512 + hc;
    const float* Wb = uwb + ((size_t)(b << 9)) * 512 + 256 + hc;

    const int srow = tid >> 3;
    const int sc4 = (tid & 7) << 2;
    *(f4*)&sUi[srow][sc4] = *(const f4*)&Ub[(size_t)(i0 + srow) * 512 + sc4];
    *(f4*)&sWi[srow][sc4] = *(const f4*)&Wb[(size_t)(i0 + srow) * 512 + sc4];
    *(f4*)&sUj[srow][sc4] = *(const f4*)&Ub[(size_t)(j0 + srow) * 512 + sc4];
    *(f4*)&sWj[srow][sc4] = *(const f4*)&Wb[(size_t)(j0 + srow) * 512 + sc4];
    if (tid < 8) *(f4*)&sV[tid << 2] = *(const f4*)&v[hc + (tid << 2)];
    __syncthreads();

    const int ty = tid >> 5;   // 0..15
    const int tx = tid & 31;   // 0..31

    // direction 1: P[i0 + ty+16d, j0 + tx+32e]
    float a1[4][2];
#pragma unroll
    for (int d = 0; d < 4; ++d)
#pragma unroll
        for (int e = 0; e < 2; ++e) a1[d][e] = 0.f;
#pragma unroll
    for (int h8 = 0; h8 < 32; h8 += 8) {
        const f4 vv0 = *(const f4*)&sV[h8];
        const f4 vv1 = *(const f4*)&sV[h8 + 4];
        f4 w0[2], w1[2];
#pragma unroll
        for (int e = 0; e < 2; ++e) {
            w0[e] = *(const f4*)&sWj[tx + (e << 5)][h8];
            w1[e] = *(const f4*)&sWj[tx + (e << 5)][h8 + 4];
        }
#pragma unroll
        for (int d = 0; d < 4; ++d) {
            const f4 u0 = *(const f4*)&sUi[ty + (d << 4)][h8];
            const f4 u1 = *(const f4*)&sUi[ty + (d << 4)][h8 + 4];
#pragma unroll
            for (int e = 0; e < 2; ++e) TREE8(u0, u1, w0[e], w1[e], vv0, vv1, a1[d][e])
        }
    }

    // direction 2 (off-diag only): P[j0 + tx+32e, i0 + ty+16d]
    float a2[2][4];
#pragma unroll
    for (int e = 0; e < 2; ++e)
#pragma unroll
        for (int d = 0; d < 4; ++d) a2[e][d] = 0.f;
    if (!diag) {
#pragma unroll
        for (int h8 = 0; h8 < 32; h8 += 8) {
            const f4 vv0 = *(const f4*)&sV[h8];
            const f4 vv1 = *(const f4*)&sV[h8 + 4];
            f4 wi0[4], wi1[4];
#pragma unroll
            for (int d = 0; d < 4; ++d) {
                wi0[d] = *(const f4*)&sWi[ty + (d << 4)][h8];
                wi1[d] = *(const f4*)&sWi[ty + (d << 4)][h8 + 4];
            }
#pragma unroll
            for (int e = 0; e < 2; ++e) {
                const f4 u0 = *(const f4*)&sUj[tx + (e << 5)][h8];
                const f4 u1 = *(const f4*)&sUj[tx + (e << 5)][h8 + 4];
#pragma unroll
                for (int d = 0; d < 4; ++d) TREE8(u0, u1, wi0[d], wi1[d], vv0, vv1, a2[e][d])
            }
        }
    }

    __syncthreads();   // staging arrays dead; T may overwrite

    if (diag) {
#pragma unroll
        for (int d = 0; d < 4; ++d)
#pragma unroll
            for (int e = 0; e < 2; ++e)
                T[ty + (d << 4)][tx + (e << 5)] = a1[d][e];
        __syncthreads();
#pragma unroll
        for (int d = 0; d < 4; ++d)
#pragma unroll
            for (int e = 0; e < 2; ++e) {
                const int r = ty + (d << 4), c = tx + (e << 5);
                const float val = -(T[r][c] + T[c][r]) * S8;
                atomicAdd(&out[(size_t)((b << 9) + i0 + r) * 512 + j0 + c], val);
            }
    } else {
#pragma unroll
        for (int d = 0; d < 4; ++d)
#pragma unroll
            for (int e = 0; e < 2; ++e) {
                const int r = ty + (d << 4), c = tx + (e << 5);
                const float val = -(a1[d][e] + a2[e][d]) * S8;
                atomicAdd(&out[(size_t)((b << 9) + i0 + r) * 512 + j0 + c], val);
                T[c][r] = val;
            }
        __syncthreads();
#pragma unroll
        for (int k = 0; k < 8; ++k) {
            const int idx = tid + (k << 9);
            const int m = idx >> 6, n = idx & 63;
            atomicAdd(&out[(size_t)((b << 9) + j0 + m) * 512 + i0 + n], T[m][n]);
        }
    }
}

extern "C" void kernel_launch(void* const* d_in, const int* in_sizes, int n_in,
                              void* d_out, int out_size, void* d_ws, size_t ws_size,
                              hipStream_t stream) {
    const float* X  = (const float*)d_in[0];
    // d_in[1] = Y (unused)
    const float* W1 = (const float*)d_in[2];
    const float* b1 = (const float*)d_in[3];
    const float* W2 = (const float*)d_in[4];
    const float* b2 = (const float*)d_in[5];
    const float* Wq = (const float*)d_in[6];
    const float* bq = (const float*)d_in[7];
    const float* Wk = (const float*)d_in[8];
    const float* bk = (const float*)d_in[9];
    const float* v  = (const float*)d_in[10];
    // d_in[11] = k (unused)

    float* ws  = (float*)d_ws;
    float* h1  = ws;                 // 2048*256 = 524288 f
    float* uwb = ws + 524288;        // 2048*512 = 1048576 f
    float* Wc  = ws + 1572864;       // 512*256  = 131072 f
    float* bc  = ws + 1703936;       // 512 f
    float* out = (float*)d_out;

    // fused: h1 = tanh(X@W1^T+b1); Wc/bc fold; blocks [160,416) init out = Sv
    gemm_stage1<<<416, 256, 0, stream>>>(X, W1, b1, Wq, Wk, W2, b2, bq, bk, v,
                                         h1, Wc, bc, out);
    // uwb[:, :256] = min(exp2(C2*Q - 8), 4), uwb[:, 256:] = min(exp2(C2*K), 1024)
    gemm_fullk<2><<<dim3(32, 8), 256, 0, stream>>>(h1, Wc, Wc + 65536, bc,
                                                   bc + 256, uwb, 512);
    // out[i,j] -= (P_ij + P_ji) over triangular tile pairs x 8 h-chunks
    pairwise_tri<<<1152, 512, 0, stream>>>(uwb, v, out);
}

// Round 12
// 59.078 us; speedup vs baseline: 5.8243x; 5.8243x over previous
//
#include <hip/hip_runtime.h>

// Problem: B=4, N=512, D=256, H=256, M = B*N = 2048
// out[b,i,j] = 0.5*(E + E^T),  E[b,i,j] = sum_h v[h]*tanh(Q[b,i,h]+K[b,j,h])
// tanh(q+k) = 1 - 2/(1+e^{2q}e^{2k}); u=exp2(C2*q), w=exp2(C2*k), C2=2*log2(e)
// P_ij = sum_h v_h/(1+u_ih w_jh);  out_ij = Sv - P_ij - P_ji
// 8-way rcp batching (1 rcp / 8 terms) via common-denominator tree.
// Overflow: u pre-scaled 2^-8 (clamp 4), w clamp 1024; leaf A=fma(u',w,2^-8);
//   M = prod8 <= 4096^8 ~ 8e28 safe; fold 2^-8 into final store.
// Round 12: NO ATOMICS (r11 lesson: 17M global atomicAdds -> 670MB RMW
// traffic, 324us). Pairwise writes 4 plain Ep slices; sym sums + transposes.

typedef float f4 __attribute__((ext_vector_type(4)));
typedef float f32x4 __attribute__((ext_vector_type(4)));
typedef __bf16 bf16x8 __attribute__((ext_vector_type(8)));

#define C2F 2.8853900817779268f
#define S8  0.00390625f   // 2^-8

__device__ inline unsigned short f2bf(float f) {
    unsigned u = __float_as_uint(f);
    unsigned r = (u + 0x7fffu + ((u >> 16) & 1u)) >> 16;
    return (unsigned short)r;
}
__device__ inline float bf2f(unsigned short h) {
    return __uint_as_float(((unsigned)h) << 16);
}

__device__ inline void split4(const f4 a, unsigned short* hp, unsigned short* lp) {
    unsigned short h[4], l[4];
#pragma unroll
    for (int t = 0; t < 4; ++t) {
        h[t] = f2bf(a[t]);
        l[t] = f2bf(a[t] - bf2f(h[t]));
    }
    uint2 hv, lv;
    hv.x = (unsigned)h[0] | ((unsigned)h[1] << 16);
    hv.y = (unsigned)h[2] | ((unsigned)h[3] << 16);
    lv.x = (unsigned)l[0] | ((unsigned)l[1] << 16);
    lv.y = (unsigned)l[2] | ((unsigned)l[3] << 16);
    *(uint2*)hp = hv;
    *(uint2*)lp = lv;
}

// ---------------------------------------------------------------------------
// gemm_fullk: C[m,n] = act(sum_k A[m,k]*Wsel[n,k] + bias[n]), K=256 resident.
// ACT==2: col<256 -> min(exp2(C2*x-8),4); col>=256 -> min(exp2(C2*x),1024)
// ---------------------------------------------------------------------------
template <int ACT>
__global__ __launch_bounds__(256) void gemm_fullk(
    const float* __restrict__ A, const float* __restrict__ Wa,
    const float* __restrict__ Wb, const float* __restrict__ ba,
    const float* __restrict__ bb2, float* __restrict__ C, int Nn) {
    __shared__ unsigned short sAhi[64][264];
    __shared__ unsigned short sAlo[64][264];
    __shared__ unsigned short sBhi[64][264];
    __shared__ unsigned short sBlo[64][264];

    const int tid = threadIdx.x;
    const int m0 = blockIdx.x << 6;
    const int n0 = blockIdx.y << 6;

    const float* Atile = A + (size_t)m0 * 256;
    const float* Wtile = (n0 < 256) ? (Wa + (size_t)n0 * 256)
                                    : (Wb + (size_t)(n0 - 256) * 256);
    const int col4 = (tid & 63) << 2;
    const int rgrp = tid >> 6;
#pragma unroll
    for (int t = 0; t < 16; ++t) {
        const int row = (t << 2) + rgrp;
        f4 av = *(const f4*)&Atile[(size_t)row * 256 + col4];
        f4 wv = *(const f4*)&Wtile[(size_t)row * 256 + col4];
        split4(av, &sAhi[row][col4], &sAlo[row][col4]);
        split4(wv, &sBhi[row][col4], &sBlo[row][col4]);
    }
    __syncthreads();

    const int lane = tid & 63;
    const int wav = tid >> 6;
    const int wm = wav >> 1, wn = wav & 1;
    const int fr = lane & 15;
    const int fks = (lane >> 4) << 3;

    f32x4 acc[2][2];
#pragma unroll
    for (int i = 0; i < 2; ++i)
#pragma unroll
        for (int j = 0; j < 2; ++j) acc[i][j] = (f32x4){0.f, 0.f, 0.f, 0.f};

#pragma unroll
    for (int kt = 0; kt < 256; kt += 32) {
        bf16x8 ah[2], al[2], bh[2], bl[2];
#pragma unroll
        for (int s = 0; s < 2; ++s) {
            ah[s] = *(const bf16x8*)&sAhi[(wm << 5) + (s << 4) + fr][kt + fks];
            al[s] = *(const bf16x8*)&sAlo[(wm << 5) + (s << 4) + fr][kt + fks];
            bh[s] = *(const bf16x8*)&sBhi[(wn << 5) + (s << 4) + fr][kt + fks];
            bl[s] = *(const bf16x8*)&sBlo[(wn << 5) + (s << 4) + fr][kt + fks];
        }
#pragma unroll
        for (int i = 0; i < 2; ++i)
#pragma unroll
            for (int j = 0; j < 2; ++j) {
                acc[i][j] = __builtin_amdgcn_mfma_f32_16x16x32_bf16(ah[i], bh[j], acc[i][j], 0, 0, 0);
                acc[i][j] = __builtin_amdgcn_mfma_f32_16x16x32_bf16(ah[i], bl[j], acc[i][j], 0, 0, 0);
                acc[i][j] = __builtin_amdgcn_mfma_f32_16x16x32_bf16(al[i], bh[j], acc[i][j], 0, 0, 0);
            }
    }

    const int rbase = (lane >> 4) << 2;
#pragma unroll
    for (int i = 0; i < 2; ++i) {
#pragma unroll
        for (int j = 0; j < 2; ++j) {
            const int gcol = n0 + (wn << 5) + (j << 4) + fr;
            const float bias = (ACT == 2 && gcol >= 256) ? bb2[gcol - 256] : ba[gcol];
#pragma unroll
            for (int q = 0; q < 4; ++q) {
                const int grow = m0 + (wm << 5) + (i << 4) + rbase + q;
                float x = acc[i][j][q] + bias;
                if (ACT == 1)
                    x = 1.0f - 2.0f * __builtin_amdgcn_rcpf(
                                          1.0f + __builtin_amdgcn_exp2f(C2F * x));
                if (ACT == 2) {
                    if (gcol < 256)
                        x = fminf(__builtin_amdgcn_exp2f(C2F * x - 8.0f), 4.0f);
                    else
                        x = fminf(__builtin_amdgcn_exp2f(C2F * x), 1024.0f);
                }
                C[(size_t)grow * Nn + gcol] = x;
            }
        }
    }
}

// ---------------------------------------------------------------------------
// gemm_stage1: fused launch.
//  blocks [0,128): h1 = tanh(X @ W1^T + b1)
//  blocks [128,160): Wc = [Wq;Wk] @ W2 (B not transp.), bc = Asel@b2 + bias
// ---------------------------------------------------------------------------
__global__ __launch_bounds__(256) void gemm_stage1(
    const float* __restrict__ X, const float* __restrict__ W1,
    const float* __restrict__ b1, const float* __restrict__ Wq,
    const float* __restrict__ Wk, const float* __restrict__ W2,
    const float* __restrict__ b2, const float* __restrict__ bq,
    const float* __restrict__ bk, float* __restrict__ h1,
    float* __restrict__ Wc, float* __restrict__ bc) {
    __shared__ unsigned short sAhi[64][264];
    __shared__ unsigned short sAlo[64][264];
    __shared__ unsigned short sBhi[64][264];
    __shared__ unsigned short sBlo[64][264];
    __shared__ float sred[64][4];

    const int tid = threadIdx.x;
    const bool is_nt = (blockIdx.x >= 128);
    const int blk = is_nt ? (blockIdx.x - 128) : blockIdx.x;
    const int m0 = (blk >> 2) << 6;
    const int n0 = (blk & 3) << 6;

    const int col4 = (tid & 63) << 2;
    const int rgrp = tid >> 6;

    if (!is_nt) {
        const float* Atile = X + (size_t)m0 * 256;
        const float* Wtile = W1 + (size_t)n0 * 256;
#pragma unroll
        for (int t = 0; t < 16; ++t) {
            const int row = (t << 2) + rgrp;
            f4 av = *(const f4*)&Atile[(size_t)row * 256 + col4];
            f4 wv = *(const f4*)&Wtile[(size_t)row * 256 + col4];
            split4(av, &sAhi[row][col4], &sAlo[row][col4]);
            split4(wv, &sBhi[row][col4], &sBlo[row][col4]);
        }
    } else {
        const float* Atile = (m0 < 256) ? (Wq + (size_t)m0 * 256)
                                        : (Wk + (size_t)(m0 - 256) * 256);
#pragma unroll
        for (int t = 0; t < 16; ++t) {
            const int row = (t << 2) + rgrp;
            f4 av = *(const f4*)&Atile[(size_t)row * 256 + col4];
            split4(av, &sAhi[row][col4], &sAlo[row][col4]);
        }
        const int c4 = (tid & 15) << 2;
        const int kg = tid >> 4;
#pragma unroll
        for (int t = 0; t < 16; ++t) {
            const int k = (t << 4) + kg;
            f4 wv = *(const f4*)&W2[(size_t)k * 256 + n0 + c4];
#pragma unroll
            for (int q = 0; q < 4; ++q) {
                unsigned short hi = f2bf(wv[q]);
                sBhi[c4 + q][k] = hi;
                sBlo[c4 + q][k] = f2bf(wv[q] - bf2f(hi));
            }
        }
    }
    __syncthreads();

    const int lane = tid & 63;
    const int wav = tid >> 6;
    const int wm = wav >> 1, wn = wav & 1;
    const int fr = lane & 15;
    const int fks = (lane >> 4) << 3;

    f32x4 acc[2][2];
#pragma unroll
    for (int i = 0; i < 2; ++i)
#pragma unroll
        for (int j = 0; j < 2; ++j) acc[i][j] = (f32x4){0.f, 0.f, 0.f, 0.f};

#pragma unroll
    for (int kt = 0; kt < 256; kt += 32) {
        bf16x8 ah[2], al[2], bh[2], bl[2];
#pragma unroll
        for (int s = 0; s < 2; ++s) {
            ah[s] = *(const bf16x8*)&sAhi[(wm << 5) + (s << 4) + fr][kt + fks];
            al[s] = *(const bf16x8*)&sAlo[(wm << 5) + (s << 4) + fr][kt + fks];
            bh[s] = *(const bf16x8*)&sBhi[(wn << 5) + (s << 4) + fr][kt + fks];
            bl[s] = *(const bf16x8*)&sBlo[(wn << 5) + (s << 4) + fr][kt + fks];
        }
#pragma unroll
        for (int i = 0; i < 2; ++i)
#pragma unroll
            for (int j = 0; j < 2; ++j) {
                acc[i][j] = __builtin_amdgcn_mfma_f32_16x16x32_bf16(ah[i], bh[j], acc[i][j], 0, 0, 0);
                acc[i][j] = __builtin_amdgcn_mfma_f32_16x16x32_bf16(ah[i], bl[j], acc[i][j], 0, 0, 0);
                acc[i][j] = __builtin_amdgcn_mfma_f32_16x16x32_bf16(al[i], bh[j], acc[i][j], 0, 0, 0);
            }
    }

    const int rbase = (lane >> 4) << 2;
    if (!is_nt) {
#pragma unroll
        for (int i = 0; i < 2; ++i)
#pragma unroll
            for (int j = 0; j < 2; ++j) {
                const int gcol = n0 + (wn << 5) + (j << 4) + fr;
                const float bias = b1[gcol];
#pragma unroll
                for (int q = 0; q < 4; ++q) {
                    const int grow = m0 + (wm << 5) + (i << 4) + rbase + q;
                    float x = acc[i][j][q] + bias;
                    x = 1.0f - 2.0f * __builtin_amdgcn_rcpf(
                                          1.0f + __builtin_amdgcn_exp2f(C2F * x));
                    h1[(size_t)grow * 256 + gcol] = x;
                }
            }
    } else {
#pragma unroll
        for (int i = 0; i < 2; ++i)
#pragma unroll
            for (int j = 0; j < 2; ++j) {
                const int gcol = n0 + (wn << 5) + (j << 4) + fr;
#pragma unroll
                for (int q = 0; q < 4; ++q) {
                    const int grow = m0 + (wm << 5) + (i << 4) + rbase + q;
                    Wc[(size_t)grow * 256 + gcol] = acc[i][j][q];
                }
            }
        if ((blk & 3) == 0) {
            const int rr = tid >> 2;
            const int part = (tid & 3) << 6;
            const int grow = m0 + rr;
            const float* Ar = (grow < 256) ? &Wq[(size_t)grow * 256]
                                           : &Wk[(size_t)(grow - 256) * 256];
            float s = 0.f;
#pragma unroll
            for (int e = 0; e < 64; e += 4) {
                f4 a = *(const f4*)&Ar[part + e];
                f4 bv = *(const f4*)&b2[part + e];
                s += a[0] * bv[0] + a[1] * bv[1] + a[2] * bv[2] + a[3] * bv[3];
            }
            sred[rr][tid & 3] = s;
            __syncthreads();
            if (tid < 64) {
                float bias = sred[tid][0] + sred[tid][1] + sred[tid][2] + sred[tid][3];
                const int g2 = m0 + tid;
                bias += (g2 < 256) ? bq[g2] : bk[g2 - 256];
                bc[g2] = bias;
            }
        }
    }
}

// 8-way common-denominator tree: ACCV += sum_{t=0..7} v_t / A_t
#define TREE8(u0, u1, wv0, wv1, vv0, vv1, ACCV)                              \
    {                                                                        \
        const float A0 = fmaf(u0.x, wv0.x, S8);                              \
        const float A1 = fmaf(u0.y, wv0.y, S8);                              \
        const float A2 = fmaf(u0.z, wv0.z, S8);                              \
        const float A3 = fmaf(u0.w, wv0.w, S8);                              \
        const float A4 = fmaf(u1.x, wv1.x, S8);                              \
        const float A5 = fmaf(u1.y, wv1.y, S8);                              \
        const float A6 = fmaf(u1.z, wv1.z, S8);                              \
        const float A7 = fmaf(u1.w, wv1.w, S8);                              \
        const float m01 = A0 * A1, m23 = A2 * A3;                            \
        const float m45 = A4 * A5, m67 = A6 * A7;                            \
        const float t01 = fmaf(vv0.x, A1, vv0.y * A0);                       \
        const float t23 = fmaf(vv0.z, A3, vv0.w * A2);                       \
        const float t45 = fmaf(vv1.x, A5, vv1.y * A4);                       \
        const float t67 = fmaf(vv1.z, A7, vv1.w * A6);                       \
        const float m03 = m01 * m23, m47 = m45 * m67;                        \
        const float t03 = fmaf(t01, m23, t23 * m01);                         \
        const float t47 = fmaf(t45, m67, t67 * m45);                         \
        const float M = m03 * m47;                                           \
        const float N = fmaf(t03, m47, t47 * m03);                           \
        ACCV = fmaf(N, __builtin_amdgcn_rcpf(M), ACCV);                      \
    }

// ---------------------------------------------------------------------------
// pairwise: per (b, i-tile, j-tile, 64-h chunk) block writes (plain stores)
//   Ep[chunk][b,i,j] = sum_{h in chunk} v_h/(1+u_ih w_jh)  (scaled by 2^8)
// 256 thr, 64x64 tile, 4x4 outputs/thread, 8-way tree. LDS ~35 KB.
// ---------------------------------------------------------------------------
__global__ __launch_bounds__(256, 4) void pairwise_kernel(
    const float* __restrict__ uwb, const float* __restrict__ v,
    float* __restrict__ Ep) {
    __shared__ float sU[64][68];
    __shared__ float sW[64][68];
    __shared__ float sV[64];

    const int tid = threadIdx.x;
    const int bb = blockIdx.x;       // 1024 = (4b * 64 tiles) * 4 h-chunks
    const int hcs = bb & 3;
    const int hc = hcs << 6;
    const int tt = bb >> 2;
    const int b = tt >> 6;
    const int i0 = ((tt >> 3) & 7) << 6;
    const int j0 = (tt & 7) << 6;

    const float* ubase = uwb + (size_t)((b << 9) + i0) * 512 + hc;
    const float* wbase = uwb + (size_t)((b << 9) + j0) * 512 + 256 + hc;

    const int srow = tid >> 2;          // 0..63
    const int sc16 = (tid & 3) << 4;    // 0,16,32,48
#pragma unroll
    for (int t = 0; t < 4; ++t) {
        *(f4*)&sU[srow][sc16 + (t << 2)] =
            *(const f4*)&ubase[(size_t)srow * 512 + sc16 + (t << 2)];
        *(f4*)&sW[srow][sc16 + (t << 2)] =
            *(const f4*)&wbase[(size_t)srow * 512 + sc16 + (t << 2)];
    }
    if (tid < 16) *(f4*)&sV[tid << 2] = *(const f4*)&v[hc + (tid << 2)];
    __syncthreads();

    const int ty = tid >> 4;   // 0..15: rows ty+16d
    const int tx = tid & 15;   // 0..15: cols tx+16e

    float acc[4][4];
#pragma unroll
    for (int d = 0; d < 4; ++d)
#pragma unroll
        for (int e = 0; e < 4; ++e) acc[d][e] = 0.f;

#pragma unroll 2
    for (int h8 = 0; h8 < 64; h8 += 8) {
        const f4 vv0 = *(const f4*)&sV[h8];
        const f4 vv1 = *(const f4*)&sV[h8 + 4];
        f4 w0[4], w1[4];
#pragma unroll
        for (int e = 0; e < 4; ++e) {
            w0[e] = *(const f4*)&sW[tx + (e << 4)][h8];
            w1[e] = *(const f4*)&sW[tx + (e << 4)][h8 + 4];
        }
#pragma unroll
        for (int d = 0; d < 4; ++d) {
            const f4 u0 = *(const f4*)&sU[ty + (d << 4)][h8];
            const f4 u1 = *(const f4*)&sU[ty + (d << 4)][h8 + 4];
#pragma unroll
            for (int e = 0; e < 4; ++e) TREE8(u0, u1, w0[e], w1[e], vv0, vv1, acc[d][e])
        }
    }

    float* ep = Ep + (size_t)hcs * 1048576 + (size_t)((b << 9) + i0) * 512 + j0;
#pragma unroll
    for (int d = 0; d < 4; ++d)
#pragma unroll
        for (int e = 0; e < 4; ++e)
            ep[(size_t)(ty + (d << 4)) * 512 + tx + (e << 4)] = acc[d][e];
}

// out[b,i,j] = Sv - 2^-8 * (sum_s Ep_s[b,i,j] + sum_s Ep_s[b,j,i])
__global__ __launch_bounds__(256) void sym_kernel(const float* __restrict__ Ep,
                                                  const float* __restrict__ v,
                                                  float* __restrict__ out) {
    __shared__ float t1[64][65];
    __shared__ float t2[64][65];
    __shared__ float red[4];

    const int tid = threadIdx.x;
    const int lane = tid & 63, wv = tid >> 6;

    float x = v[tid];
#pragma unroll
    for (int o = 32; o > 0; o >>= 1) x += __shfl_xor(x, o, 64);
    if (lane == 0) red[wv] = x;

    const int bb = blockIdx.x;
    const int b = bb >> 6;
    const int i0 = ((bb >> 3) & 7) << 6;
    const int j0 = (bb & 7) << 6;

    for (int idx = tid; idx < 4096; idx += 256) {
        const int r = idx >> 6, c = idx & 63;
        const size_t o1 = (size_t)((b << 9) + i0 + r) * 512 + j0 + c;
        const size_t o2 = (size_t)((b << 9) + j0 + r) * 512 + i0 + c;
        t1[r][c] = (Ep[o1] + Ep[o1 + 1048576]) +
                   (Ep[o1 + 2097152] + Ep[o1 + 3145728]);
        t2[r][c] = (Ep[o2] + Ep[o2 + 1048576]) +
                   (Ep[o2 + 2097152] + Ep[o2 + 3145728]);
    }
    __syncthreads();
    const float Sv = red[0] + red[1] + red[2] + red[3];
    for (int idx = tid; idx < 4096; idx += 256) {
        const int r = idx >> 6, c = idx & 63;
        out[(size_t)((b << 9) + i0 + r) * 512 + j0 + c] =
            Sv - (t1[r][c] + t2[c][r]) * S8;
    }
}

extern "C" void kernel_launch(void* const* d_in, const int* in_sizes, int n_in,
                              void* d_out, int out_size, void* d_ws, size_t ws_size,
                              hipStream_t stream) {
    const float* X  = (const float*)d_in[0];
    // d_in[1] = Y (unused)
    const float* W1 = (const float*)d_in[2];
    const float* b1 = (const float*)d_in[3];
    const float* W2 = (const float*)d_in[4];
    const float* b2 = (const float*)d_in[5];
    const float* Wq = (const float*)d_in[6];
    const float* bq = (const float*)d_in[7];
    const float* Wk = (const float*)d_in[8];
    const float* bk = (const float*)d_in[9];
    const float* v  = (const float*)d_in[10];
    // d_in[11] = k (unused)

    float* ws  = (float*)d_ws;
    float* h1  = ws;                 // 2048*256 = 524288 f
    float* uwb = ws + 524288;        // 2048*512 = 1048576 f
    float* Wc  = ws + 1572864;       // 512*256  = 131072 f
    float* bc  = ws + 1703936;       // 512 f
    float* Ep  = ws + 1704448;       // 4*1048576 f (plain-store slices)
    float* out = (float*)d_out;

    // fused: h1 = tanh(X@W1^T+b1); Wc = [Wq;Wk]@W2, bc = [..]@b2 + bias
    gemm_stage1<<<160, 256, 0, stream>>>(X, W1, b1, Wq, Wk, W2, b2, bq, bk,
                                         h1, Wc, bc);
    // uwb[:, :256] = min(exp2(C2*Q - 8), 4), uwb[:, 256:] = min(exp2(C2*K), 1024)
    gemm_fullk<2><<<dim3(32, 8), 256, 0, stream>>>(h1, Wc, Wc + 65536, bc,
                                                   bc + 256, uwb, 512);
    // Ep[hc][b,i,j] = 2^8 * sum_{h in chunk} v_h/(1+u w)   (plain stores)
    pairwise_kernel<<<1024, 256, 0, stream>>>(uwb, v, Ep);
    // out = Sv - 2^-8*(sum Ep + (sum Ep)^T)
    sym_kernel<<<256, 256, 0, stream>>>(Ep, v, out);
}